// Round 5
// baseline (532.816 us; speedup 1.0000x reference)
//
#include <hip/hip_runtime.h>

#define EMBED 1024
#define HEADS 16
#define HDIM  64

typedef __attribute__((ext_vector_type(8))) short bf16x8;
typedef __attribute__((ext_vector_type(4))) float f32x4;

#define AS1 __attribute__((address_space(1)))
#define AS3 __attribute__((address_space(3)))

#if __has_builtin(__builtin_amdgcn_exp2f)
#define EXP2F(x) __builtin_amdgcn_exp2f(x)
#else
#define EXP2F(x) exp2f(x)
#endif

__device__ __forceinline__ unsigned bf16_rne(float f) {
    unsigned u = __float_as_uint(f);
    return (u + 0x7FFFu + ((u >> 16) & 1u)) >> 16;
}

// ---------------------------------------------------------------------------
// Kernel 0: split fp32 -> bf16 hi + bf16 lo.
// ---------------------------------------------------------------------------
__global__ __launch_bounds__(256)
void split_bf16(const float* __restrict__ in, short* __restrict__ hi,
                short* __restrict__ lo, int n)
{
    int i = (blockIdx.x * 256 + threadIdx.x) * 8;
    if (i >= n) return;
    float4 a = *(const float4*)(in + i);
    float4 b = *(const float4*)(in + i + 4);
    float f[8] = {a.x, a.y, a.z, a.w, b.x, b.y, b.z, b.w};
    union { unsigned short us[8]; uint4 v; } H, L;
#pragma unroll
    for (int e = 0; e < 8; ++e) {
        unsigned hb = bf16_rne(f[e]);
        H.us[e] = (unsigned short)hb;
        float r = f[e] - __uint_as_float(hb << 16);
        L.us[e] = (unsigned short)bf16_rne(r);
    }
    *(uint4*)(hi + i) = H.v;
    *(uint4*)(lo + i) = L.v;
}

// ---------------------------------------------------------------------------
// Kernel 1: QKV projection, bf16-split MFMA (fp32-accurate, 3 passes).
// Epilogue round-trips C through LDS (XOR-swizzled) for coalesced bf16 stores.
// Q scaled by (1/8)*log2(e) so attention softmax can use exp2.
// ---------------------------------------------------------------------------
__global__ __launch_bounds__(256)
void qkv_mfma(const short* __restrict__ Xh, const short* __restrict__ Xl,
              const short* __restrict__ Wh, const short* __restrict__ Wl,
              const float* __restrict__ bq, const float* __restrict__ bk,
              const float* __restrict__ bv,
              short* __restrict__ Qb, short* __restrict__ Kb, short* __restrict__ Vt)
{
    __shared__ short sh[16384];   // staging: Ah|Al|Bh|Bl (4 x 4096 shorts); epilogue tile

    const int t  = threadIdx.x;
    const int nt = blockIdx.x;          // 0..23
    const int mt = blockIdx.y;          // 0..63
    const int m0 = mt * 128, n0 = nt * 128;

    const int lane = t & 63, quad = lane >> 4, l16 = lane & 15;
    const int w = t >> 6, wm = w >> 1, wn = w & 1;

    const int r0 = t & 127, s0 = t >> 7;
    const short* gA_h = Xh + (size_t)(m0 + r0) * EMBED + s0 * 8;
    const short* gA_l = Xl + (size_t)(m0 + r0) * EMBED + s0 * 8;
    const short* gB_h = Wh + (size_t)(n0 + r0) * EMBED + s0 * 8;
    const short* gB_l = Wl + (size_t)(n0 + r0) * EMBED + s0 * 8;

    f32x4 acc[4][4];
#pragma unroll
    for (int i = 0; i < 4; ++i)
#pragma unroll
        for (int j = 0; j < 4; ++j) acc[i][j] = (f32x4){0.f, 0.f, 0.f, 0.f};

    for (int k0 = 0; k0 < EMBED; k0 += 32) {
        __syncthreads();
        __builtin_amdgcn_global_load_lds((const AS1 void*)(gA_h + k0),      (AS3 void*)&sh[t * 8],                16, 0, 0);
        __builtin_amdgcn_global_load_lds((const AS1 void*)(gA_h + k0 + 16), (AS3 void*)&sh[(t + 256) * 8],        16, 0, 0);
        __builtin_amdgcn_global_load_lds((const AS1 void*)(gA_l + k0),      (AS3 void*)&sh[4096 + t * 8],         16, 0, 0);
        __builtin_amdgcn_global_load_lds((const AS1 void*)(gA_l + k0 + 16), (AS3 void*)&sh[4096 + (t + 256) * 8], 16, 0, 0);
        __builtin_amdgcn_global_load_lds((const AS1 void*)(gB_h + k0),      (AS3 void*)&sh[8192 + t * 8],         16, 0, 0);
        __builtin_amdgcn_global_load_lds((const AS1 void*)(gB_h + k0 + 16), (AS3 void*)&sh[8192 + (t + 256) * 8], 16, 0, 0);
        __builtin_amdgcn_global_load_lds((const AS1 void*)(gB_l + k0),      (AS3 void*)&sh[12288 + t * 8],        16, 0, 0);
        __builtin_amdgcn_global_load_lds((const AS1 void*)(gB_l + k0 + 16), (AS3 void*)&sh[12288 + (t + 256) * 8],16, 0, 0);
        __syncthreads();

        bf16x8 ah[4], al[4], bh[4], bl[4];
#pragma unroll
        for (int mi = 0; mi < 4; ++mi) {
            const int c = quad * 128 + wm * 64 + mi * 16 + l16;
            ah[mi] = *(const bf16x8*)&sh[c * 8];
            al[mi] = *(const bf16x8*)&sh[4096 + c * 8];
        }
#pragma unroll
        for (int ni = 0; ni < 4; ++ni) {
            const int c = quad * 128 + wn * 64 + ni * 16 + l16;
            bh[ni] = *(const bf16x8*)&sh[8192 + c * 8];
            bl[ni] = *(const bf16x8*)&sh[12288 + c * 8];
        }
#pragma unroll
        for (int mi = 0; mi < 4; ++mi)
#pragma unroll
            for (int ni = 0; ni < 4; ++ni) {
                acc[mi][ni] = __builtin_amdgcn_mfma_f32_16x16x32_bf16(ah[mi], bh[ni], acc[mi][ni], 0, 0, 0);
                acc[mi][ni] = __builtin_amdgcn_mfma_f32_16x16x32_bf16(ah[mi], bl[ni], acc[mi][ni], 0, 0, 0);
                acc[mi][ni] = __builtin_amdgcn_mfma_f32_16x16x32_bf16(al[mi], bh[ni], acc[mi][ni], 0, 0, 0);
            }
    }

    __syncthreads();   // main-loop LDS reads done; reuse sh for epilogue

    const int mat = n0 >> 10;                 // 0=q 1=k 2=v
    const float* bias = (mat == 0) ? bq : (mat == 1) ? bk : bv;
    const int bidx = m0 >> 10;
    const int l0   = m0 & 1023;
    const int nm0  = n0 & 1023;
    float bias_v[4];
#pragma unroll
    for (int ni = 0; ni < 4; ++ni) bias_v[ni] = bias[nm0 + wn * 64 + ni * 16 + l16];

    if (mat == 2) {
        // V: LDS tile [n 128][m 128] bf16, 8-short granules XOR-swizzled by n&15.
        short* tile = sh;
#pragma unroll
        for (int mi = 0; mi < 4; ++mi)
#pragma unroll
            for (int ni = 0; ni < 4; ++ni) {
                const int n = wn * 64 + ni * 16 + l16;
                const int g = wm * 8 + mi * 2 + (quad >> 1);
                const int off = n * 128 + ((g ^ (n & 15)) * 8) + (quad & 1) * 4;
                const float v0 = acc[mi][ni][0] + bias_v[ni];
                const float v1 = acc[mi][ni][1] + bias_v[ni];
                const float v2 = acc[mi][ni][2] + bias_v[ni];
                const float v3 = acc[mi][ni][3] + bias_v[ni];
                uint2 w2;
                w2.x = bf16_rne(v0) | (bf16_rne(v1) << 16);
                w2.y = bf16_rne(v2) | (bf16_rne(v3) << 16);
                *(uint2*)&tile[off] = w2;
            }
        __syncthreads();
        const int n = t >> 1;
        const int nm = nm0 + n, head = nm >> 6, d = nm & 63;
        short* vp = Vt + ((size_t)(bidx * HEADS + head) * 64 + d) * 1024 + l0;
#pragma unroll
        for (int i = 0; i < 8; ++i) {
            const int c = (t & 1) * 8 + i;
            uint4 val = *(uint4*)&tile[n * 128 + ((c ^ (n & 15)) * 8)];
            *(uint4*)&vp[c * 8] = val;
        }
    } else {
        // Q/K: two passes of fp32 [m 64][n 128], 4-word granules XOR-swizzled.
        float* tile = (float*)sh;
        short* Out = (mat == 0) ? Qb : Kb;
        const float scale = (mat == 0) ? 0.125f * 1.4426950408889634f : 1.0f;
#pragma unroll
        for (int p = 0; p < 2; ++p) {
            if (p) __syncthreads();
            if (wm == p) {
#pragma unroll
                for (int mi = 0; mi < 4; ++mi)
#pragma unroll
                    for (int ni = 0; ni < 4; ++ni) {
                        const int nn = wn * 64 + ni * 16 + l16;
#pragma unroll
                        for (int r = 0; r < 4; ++r) {
                            const int mrow = mi * 16 + quad * 4 + r;
                            tile[mrow * 128 + (((nn >> 2) ^ (mrow & 31)) << 2) + (nn & 3)] =
                                (acc[mi][ni][r] + bias_v[ni]) * scale;
                        }
                    }
            }
            __syncthreads();
            const int mrow = t >> 2;
            const int l = l0 + p * 64 + mrow;
#pragma unroll
            for (int ii = 0; ii < 4; ++ii) {
                const int g0 = (t & 3) * 8 + 2 * ii;
                float4 a = *(float4*)&tile[mrow * 128 + ((g0 ^ (mrow & 31)) << 2)];
                float4 b = *(float4*)&tile[mrow * 128 + (((g0 + 1) ^ (mrow & 31)) << 2)];
                uint4 o;
                o.x = bf16_rne(a.x) | (bf16_rne(a.y) << 16);
                o.y = bf16_rne(a.z) | (bf16_rne(a.w) << 16);
                o.z = bf16_rne(b.x) | (bf16_rne(b.y) << 16);
                o.w = bf16_rne(b.z) | (bf16_rne(b.w) << 16);
                const int nm = nm0 + (t & 3) * 32 + ii * 8;
                const int head = nm >> 6, d = nm & 63;
                *(uint4*)&Out[((size_t)(bidx * HEADS + head) * 1024 + l) * 64 + d] = o;
            }
        }
    }
}

// ---------------------------------------------------------------------------
// Kernel 2: MFMA flash attention, S^T form.  Block = (qt, h, b), 4 waves x 16
// queries.  S^T = K.Q^T (softmax reduces in-lane + 2 shfl); P moved to B-frag
// layout by a 16-shfl cross-quad transform (no LDS round-trip); O^T = V^T.P.
// K/V double-buffered, one barrier per key tile.  Softmax in exp2 domain.
// ---------------------------------------------------------------------------
__global__ __launch_bounds__(256)
void attn_mfma(const short* __restrict__ Qb, const short* __restrict__ Kb,
               const short* __restrict__ Vt, float* __restrict__ out)
{
    __shared__ short smem[20480];   // Qs 4096 | Ks0 | Ks1 | Vs0 | Vs1 (4096 each)

    const int t  = threadIdx.x;
    const int qt = blockIdx.x, h = blockIdx.y, b = blockIdx.z;
    const int bh = b * HEADS + h;
    const int lane = t & 63, quad = lane >> 4, l16 = lane & 15;
    const int w = t >> 6;
    const int srow = t & 63, schunk = t >> 6;

    // Stage Q (once) and K/V tile 0
    {
        const short* gq = Qb + ((size_t)bh * 1024 + qt * 64 + srow) * 64 + schunk * 8;
        __builtin_amdgcn_global_load_lds((const AS1 void*)gq,        (AS3 void*)&smem[t * 8],         16, 0, 0);
        __builtin_amdgcn_global_load_lds((const AS1 void*)(gq + 32), (AS3 void*)&smem[(t + 256) * 8], 16, 0, 0);
        const short* gk = Kb + ((size_t)bh * 1024 + srow) * 64 + schunk * 8;
        __builtin_amdgcn_global_load_lds((const AS1 void*)gk,        (AS3 void*)&smem[4096 + t * 8],         16, 0, 0);
        __builtin_amdgcn_global_load_lds((const AS1 void*)(gk + 32), (AS3 void*)&smem[4096 + (t + 256) * 8], 16, 0, 0);
        const short* gv = Vt + ((size_t)bh * 64 + srow) * 1024 + schunk * 8;
        __builtin_amdgcn_global_load_lds((const AS1 void*)gv,        (AS3 void*)&smem[12288 + t * 8],         16, 0, 0);
        __builtin_amdgcn_global_load_lds((const AS1 void*)(gv + 32), (AS3 void*)&smem[12288 + (t + 256) * 8], 16, 0, 0);
    }
    __syncthreads();

    // Q B-frags (queries = this wave's 16), constant across kt
    bf16x8 qfrag[2];
#pragma unroll
    for (int kh = 0; kh < 2; ++kh)
        qfrag[kh] = *(const bf16x8*)&smem[((quad + 4 * kh) * 64 + w * 16 + l16) * 8];

    f32x4 O[4];
#pragma unroll
    for (int i = 0; i < 4; ++i) O[i] = (f32x4){0.f, 0.f, 0.f, 0.f};
    float m_i = -1e30f, l_i = 0.f;

    for (int kt = 0; kt < 16; ++kt) {
        const int cur = kt & 1, nxt = cur ^ 1;
        if (kt < 15) {
            const short* gk = Kb + ((size_t)bh * 1024 + (kt + 1) * 64 + srow) * 64 + schunk * 8;
            __builtin_amdgcn_global_load_lds((const AS1 void*)gk,        (AS3 void*)&smem[4096 + nxt * 4096 + t * 8],         16, 0, 0);
            __builtin_amdgcn_global_load_lds((const AS1 void*)(gk + 32), (AS3 void*)&smem[4096 + nxt * 4096 + (t + 256) * 8], 16, 0, 0);
            const short* gv = Vt + ((size_t)bh * 64 + srow) * 1024 + (kt + 1) * 64 + schunk * 8;
            __builtin_amdgcn_global_load_lds((const AS1 void*)gv,        (AS3 void*)&smem[12288 + nxt * 4096 + t * 8],         16, 0, 0);
            __builtin_amdgcn_global_load_lds((const AS1 void*)(gv + 32), (AS3 void*)&smem[12288 + nxt * 4096 + (t + 256) * 8], 16, 0, 0);
        }

        const short* Kc = &smem[4096 + cur * 4096];
        const short* Vc = &smem[12288 + cur * 4096];

        // S^T = K.Q^T : 4 m-frags (keys) x 2 k-halves (d)
        f32x4 ST[4];
#pragma unroll
        for (int mi = 0; mi < 4; ++mi) ST[mi] = (f32x4){0.f, 0.f, 0.f, 0.f};
#pragma unroll
        for (int kh = 0; kh < 2; ++kh)
#pragma unroll
            for (int mi = 0; mi < 4; ++mi) {
                const bf16x8 ka = *(const bf16x8*)&Kc[((quad + 4 * kh) * 64 + mi * 16 + l16) * 8];
                ST[mi] = __builtin_amdgcn_mfma_f32_16x16x32_bf16(ka, qfrag[kh], ST[mi], 0, 0, 0);
            }

        // Online softmax (query = l16; keys spread over in-lane 16 + 4 quads)
        float mx = -1e30f;
#pragma unroll
        for (int mi = 0; mi < 4; ++mi)
#pragma unroll
            for (int r = 0; r < 4; ++r) mx = fmaxf(mx, ST[mi][r]);
        mx = fmaxf(mx, __shfl_xor(mx, 16));
        mx = fmaxf(mx, __shfl_xor(mx, 32));
        const float mnew  = fmaxf(m_i, mx);
        const float alpha = EXP2F(m_i - mnew);
        m_i = mnew;
        float p[4][4];
        float rs = 0.f;
#pragma unroll
        for (int mi = 0; mi < 4; ++mi)
#pragma unroll
            for (int r = 0; r < 4; ++r) { p[mi][r] = EXP2F(ST[mi][r] - mnew); rs += p[mi][r]; }
        rs += __shfl_xor(rs, 16);
        rs += __shfl_xor(rs, 32);
        l_i = l_i * alpha + rs;
#pragma unroll
        for (int mi = 0; mi < 4; ++mi)
#pragma unroll
            for (int r = 0; r < 4; ++r) O[mi][r] *= alpha;

        // P: C-layout (lane=query col, rows=keys) -> B-frag via cross-quad shfl
        unsigned pk[4][2];
#pragma unroll
        for (int mi = 0; mi < 4; ++mi) {
            pk[mi][0] = bf16_rne(p[mi][0]) | (bf16_rne(p[mi][1]) << 16);
            pk[mi][1] = bf16_rne(p[mi][2]) | (bf16_rne(p[mi][3]) << 16);
        }
        const int srcA = (quad & 1) * 32 + l16;
        const int srcB = srcA + 16;
        const bool hi = quad >= 2;
        union { unsigned u[4]; bf16x8 v; } pa[2];
        {
            unsigned a00 = __shfl((int)pk[0][0], srcA), a10 = __shfl((int)pk[1][0], srcA);
            unsigned a01 = __shfl((int)pk[0][1], srcA), a11 = __shfl((int)pk[1][1], srcA);
            unsigned b00 = __shfl((int)pk[0][0], srcB), b10 = __shfl((int)pk[1][0], srcB);
            unsigned b01 = __shfl((int)pk[0][1], srcB), b11 = __shfl((int)pk[1][1], srcB);
            pa[0].u[0] = hi ? a10 : a00;  pa[0].u[1] = hi ? a11 : a01;
            pa[0].u[2] = hi ? b10 : b00;  pa[0].u[3] = hi ? b11 : b01;
            unsigned c00 = __shfl((int)pk[2][0], srcA), c10 = __shfl((int)pk[3][0], srcA);
            unsigned c01 = __shfl((int)pk[2][1], srcA), c11 = __shfl((int)pk[3][1], srcA);
            unsigned d00 = __shfl((int)pk[2][0], srcB), d10 = __shfl((int)pk[3][0], srcB);
            unsigned d01 = __shfl((int)pk[2][1], srcB), d11 = __shfl((int)pk[3][1], srcB);
            pa[1].u[0] = hi ? c10 : c00;  pa[1].u[1] = hi ? c11 : c01;
            pa[1].u[2] = hi ? d10 : d00;  pa[1].u[3] = hi ? d11 : d01;
        }

        // O^T += V^T.P : 4 m-frags (d) x 2 k-halves (keys)
#pragma unroll
        for (int kh = 0; kh < 2; ++kh)
#pragma unroll
            for (int mi = 0; mi < 4; ++mi) {
                const bf16x8 va = *(const bf16x8*)&Vc[((quad + 4 * kh) * 64 + mi * 16 + l16) * 8];
                O[mi] = __builtin_amdgcn_mfma_f32_16x16x32_bf16(va, pa[kh].v, O[mi], 0, 0, 0);
            }

        __syncthreads();   // nxt staging landed; cur reads done
    }

    // Epilogue: O^T (lane=query, rows=d) -> LDS [q 64][d 68] f32 -> coalesced
    float* Os = (float*)&smem[4096];
    const float inv = 1.0f / l_i;
#pragma unroll
    for (int mi = 0; mi < 4; ++mi) {
        f32x4 v;
#pragma unroll
        for (int r = 0; r < 4; ++r) v[r] = O[mi][r] * inv;
        *(f32x4*)&Os[(w * 16 + l16) * 68 + mi * 16 + quad * 4] = v;
    }
    __syncthreads();
    {
        const int q = t >> 2, dbase = (t & 3) * 16;
        float* op = out + ((size_t)bh * 1024 + qt * 64 + q) * 64 + dbase;
#pragma unroll
        for (int i = 0; i < 4; ++i)
            *(float4*)&op[i * 4] = *(float4*)&Os[q * 68 + dbase + i * 4];
    }
}

extern "C" void kernel_launch(void* const* d_in, const int* in_sizes, int n_in,
                              void* d_out, int out_size, void* d_ws, size_t ws_size,
                              hipStream_t stream)
{
    const float* X  = (const float*)d_in[0];
    const float* Wq = (const float*)d_in[1];
    const float* bq = (const float*)d_in[2];
    const float* Wk = (const float*)d_in[3];
    const float* bk = (const float*)d_in[4];
    const float* Wv = (const float*)d_in[5];
    const float* bv = (const float*)d_in[6];
    float* out = (float*)d_out;

    const size_t per = (size_t)8 * HEADS * 1024 * HDIM;   // 8,388,608
    short* Qb = (short*)d_ws;
    short* Kb = Qb + per;
    short* Vt = Kb + per;
    short* Xh = Vt + per;
    short* Xl = Xh + per;
    short* Wh = Xl + per;                 // 3 x 1,048,576
    short* Wl = Wh + 3 * 1048576;

    const int nX = (int)per;
    const int nW = 1048576;

    split_bf16<<<nX / (8 * 256), 256, 0, stream>>>(X,  Xh, Xl, nX);
    split_bf16<<<nW / (8 * 256), 256, 0, stream>>>(Wq, Wh,          Wl,          nW);
    split_bf16<<<nW / (8 * 256), 256, 0, stream>>>(Wk, Wh + nW,     Wl + nW,     nW);
    split_bf16<<<nW / (8 * 256), 256, 0, stream>>>(Wv, Wh + 2 * nW, Wl + 2 * nW, nW);

    qkv_mfma<<<dim3(24, 64), 256, 0, stream>>>(Xh, Xl, Wh, Wl, bq, bk, bv, Qb, Kb, Vt);
    attn_mfma<<<dim3(16, HEADS, 8), 256, 0, stream>>>(Qb, Kb, Vt, out);
}